// Round 1
// baseline (62.987 us; speedup 1.0000x reference)
//
#include <hip/hip_runtime.h>

// out[0, n*96+j, l, m] = sum_{g<24} W[n*96+j][g] * x[n*24+g, m, l]
// W[o][g] = sum_{i<9} w0[o%96, i] * w1[(o/96)*24+g, i]
//
// x:  [48][56][56]  (c, m, l)  -- l contiguous; output spatial is (l, m)
// out:[192][56][56] (o, l, m)
//
// v2: LDS x-staging removed (the tile had ZERO reuse -- each element was
// read back by exactly one thread; channel reuse lives in registers).
// Each compute thread float4-loads x[g, m, l0..l0+3] directly (same 16B
// coalescing granule as the old staged path, minus the barrier + ds
// round-trip). Thread = (m, jq); jq in 0..3 splits the 12 channels into
// 3 each -- the 4x redundant x reads across jq groups hit the same L1
// lines. x loads are issued BEFORE the weight fold so their latency
// hides under the fold's w0/w1 loads (kernel runs at 1 wave/SIMD, so
// exposed latency, not bandwidth, is the cost).

#define S    56        // spatial dim
#define SP   3136      // 56*56
#define G    24        // channels summed per group
#define JB   12        // output channels per block
#define JPT  3         // output channels per compute thread (JB / 4 jq-groups)

__global__ __launch_bounds__(256)
void conv_mix_fused(const float* __restrict__ x, const float* __restrict__ w0,
                    const float* __restrict__ w1, float* __restrict__ out) {
    __shared__ float Wl[JB * G];       // 1.1 KB
    const int bx  = blockIdx.x;        // float4 column: l0 = bx*4
    const int j0  = blockIdx.y * JB;
    const int n   = blockIdx.z;
    const int tid = threadIdx.x;

    const int  m      = tid % S;
    const int  jq     = tid / S;       // 0..3 for active threads
    const bool active = tid < 4 * S;   // 224 compute threads

    // ---- issue x loads first; latency hides under the weight fold ----
    float4 xv[G];
    if (active) {
        const float4* x4 = reinterpret_cast<const float4*>(x)
                         + (size_t)n * G * (SP / 4) + m * (S / 4) + bx;
        #pragma unroll
        for (int g = 0; g < G; ++g)
            xv[g] = x4[g * (SP / 4)];  // x[n*24+g, m, bx*4 .. bx*4+3]
    }

    // ---- per-block weight fold: Wl[j][g] = sum_i w0[j0+j,i]*w1[n*24+g,i] ----
    for (int idx = tid; idx < JB * G; idx += 256) {
        int j = idx / G, g = idx - j * G;
        float s = 0.f;
        #pragma unroll
        for (int i = 0; i < 9; ++i)
            s += w0[(j0 + j) * 9 + i] * w1[(n * G + g) * 9 + i];
        Wl[idx] = s;
    }
    __syncthreads();

    // ---- compute: thread (m, jq) -> 3 channels x 4 l-values ----
    if (active) {
        float* obase = out + (size_t)(n * 96 + j0 + jq * JPT) * SP
                     + (bx * 4) * S + m;
        #pragma unroll
        for (int j = 0; j < JPT; ++j) {
            float ax = 0.f, ay = 0.f, az = 0.f, aw = 0.f;
            #pragma unroll
            for (int g = 0; g < G; ++g) {
                float w = Wl[(jq * JPT + j) * G + g];   // LDS broadcast
                ax += w * xv[g].x;
                ay += w * xv[g].y;
                az += w * xv[g].z;
                aw += w * xv[g].w;
            }
            float* o = obase + j * SP;   // contiguous 224B per (j,l) across lanes
            o[0]     = ax;
            o[S]     = ay;
            o[2 * S] = az;
            o[3 * S] = aw;
        }
    }
}

extern "C" void kernel_launch(void* const* d_in, const int* in_sizes, int n_in,
                              void* d_out, int out_size, void* d_ws, size_t ws_size,
                              hipStream_t stream) {
    const float* x  = (const float*)d_in[0];
    const float* w0 = (const float*)d_in[1];
    const float* w1 = (const float*)d_in[2];
    float* out = (float*)d_out;
    (void)d_ws; (void)ws_size;

    dim3 grid(S / 4, 96 / JB, 2);   // (14, 8, 2) = 224 blocks
    conv_mix_fused<<<grid, 256, 0, stream>>>(x, w0, w1, out);
}